// Round 13
// baseline (172.388 us; speedup 1.0000x reference)
//
#include <hip/hip_runtime.h>
#include <hip/hip_bf16.h>
#include <cstdint>
#include <cstddef>

#define EMB_K   1024
#define EMB_C   256
#define HWB     4096        // 64*64 per batch
#define NPIX    65536       // 16*4096

typedef __bf16 bf16x8 __attribute__((ext_vector_type(8)));
typedef float  f32x4  __attribute__((ext_vector_type(4)));

__device__ __forceinline__ unsigned short bf16bits(float v) {
  __hip_bfloat16 h = __float2bfloat16(v);
  return __builtin_bit_cast(unsigned short, h);
}

// ---- emb -> bf16 row-major + fp32 norms; zero loss ----
__global__ void k_emb(const float* __restrict__ emb, unsigned short* __restrict__ emb_bf,
                      float* __restrict__ enorm, float* __restrict__ loss) {
  int k = blockIdx.x;      // 0..1023
  int c = threadIdx.x;     // 0..255
  if (k == 0 && c == 0) *loss = 0.f;
  float v = emb[(size_t)k * EMB_C + c];
  emb_bf[(size_t)k * EMB_C + c] = bf16bits(v);
  float s = v * v;
  for (int m = 32; m; m >>= 1) s += __shfl_down(s, m, 64);
  __shared__ float red[4];
  int lane = c & 63, w = c >> 6;
  if (lane == 0) red[w] = s;
  __syncthreads();
  if (c == 0) enorm[k] = red[0] + red[1] + red[2] + red[3];
}

// ================= transpose kernel: x -> A (FRAGMENT-ORDERED bf16) =================
// 1024 blocks x 512 thr, 256B LDS -> ~32 waves/CU (memory-phase occupancy; R12's
// k_out proved ~5.3 TB/s at this TLP vs 2.5 at 8 waves). Block owns 64 n.
// A layout = exactly what k_main's af load wants: 16B chunk index
//   blk*8192 + ((g*4+i)*8+s)*64 + quad*16 + lr
// where n = blk*256 + g*64 + i*16 + lr (n-local in k_main's 256-n block) and
// c = s*32 + quad*8 + j (j 0..7 inside the chunk). Per thread: 4 m-chunks are
// lr-consecutive -> one full 64B line per (thread,chunk-col). xn -> xn_g.
__global__ __launch_bounds__(512) void
k_tr(const float* __restrict__ x, unsigned short* __restrict__ A,
     float* __restrict__ xn_g) {
  __shared__ float xn_l[64];
  int t  = threadIdx.x;
  int n0 = blockIdx.x * 64;
  int b  = n0 >> 12, hw0 = n0 & 4095;
  int hwq = t & 15, c8 = t >> 4;           // hwq: 4-n quad; c8 0..31 (8 c each)
  if (t < 64) xn_l[t] = 0.f;
  __syncthreads();
  const float* xp = x + (size_t)b * (EMB_C * HWB) + hw0 + hwq * 4;
  float xn[4] = {0.f, 0.f, 0.f, 0.f};
  unsigned pk[4][4] = {};
#pragma unroll
  for (int j = 0; j < 8; ++j) {            // c = c8*8 + j
    f32x4 v = *(const f32x4*)(xp + (size_t)(c8 * 8 + j) * HWB);  // 16B/lane
#pragma unroll
    for (int m = 0; m < 4; ++m) {
      xn[m] += v[m] * v[m];
      pk[m][j >> 1] |= (unsigned)bf16bits(v[m]) << ((j & 1) * 16);
    }
  }
  int s = c8 >> 2, quad = c8 & 3;
  uint4* A16 = (uint4*)A;
#pragma unroll
  for (int m = 0; m < 4; ++m) {
    int n  = n0 + hwq * 4 + m;
    int blk = n >> 8, nl = n & 255;
    int g = nl >> 6, i = (nl >> 4) & 3, lr = nl & 15;
    A16[(size_t)blk * 8192 + ((g * 4 + i) * 8 + s) * 64 + quad * 16 + lr]
        = *(const uint4*)pk[m];
    atomicAdd(&xn_l[hwq * 4 + m], xn[m]);
  }
  __syncthreads();
  if (t < 64) xn_g[n0 + t] = xn_l[t];
}

// ---- staging: 64 rows x 256c bf16 = 32KB, XOR-swizzled 16B chunks, glds ----
// 512-thread: 2048 chunks, 4 per thread (4 vmcnt units per stage)
__device__ __forceinline__ void stage64(const unsigned short* __restrict__ rows,
                                        unsigned char* buf, int t) {
#pragma unroll
  for (int j = 0; j < 4; ++j) {
    int d = j * 512 + t;             // linear dest chunk 0..2047
    int r = d >> 5;                  // row 0..63
    int slot = d & 31;
    int c16 = ((slot >> 3) << 3) | ((slot & 7) ^ (r & 7));
    const unsigned short* src = rows + (size_t)r * EMB_C + c16 * 8;
    __builtin_amdgcn_global_load_lds(
        (const __attribute__((address_space(1))) void*)src,
        (__attribute__((address_space(3))) void*)(buf + (unsigned)(j * 8192 + (t >> 6) * 1024)),
        16, 0, 0);
  }
}

// ================= main kernel: GEMM + argmin + loss =================
// R12's proven k-loop/argmin/loss, with the prologue DELETED: af loads are 32
// fully-coalesced 1KB global reads from fragment-ordered A (no A-LDS tile, no
// pack VALU, no prologue barriers — R12's 2.36M bank conflicts were all from
// the A-tile writes). 256 blocks x 512 thr, 1 block/CU.
// LDS: [0,128K) bufs 4x32KB | cjl 4K | keys 1K | xn 1K | red
#define LDS_BYTES 137280

__global__ __launch_bounds__(512) void
k_main(const unsigned short* __restrict__ A, const unsigned short* __restrict__ embbf,
       const float* __restrict__ enorm, const float* __restrict__ xn_g,
       unsigned* __restrict__ keys_g, float* __restrict__ loss) {
  extern __shared__ char smem[];
  float*    cjl    = (float*)(smem + 131072);          // 1024 f32
  unsigned* keys_l = (unsigned*)(smem + 135168);       // 256 u32
  float*    xn_l   = (float*)(smem + 136192);          // 256 f32
  float*    red    = (float*)(smem + 137216);          // 16 f32

  int n0 = blockIdx.x * 256;
  int t = threadIdx.x, w = t >> 6, lane = t & 63;
  int quad = lane >> 4, lr = lane & 15;
  int g  = w >> 1;       // n-group 0..3 (64 n)
  int h2 = w & 1;        // k-half (32 k of each 64k tile)

  // B(0)/B(1) staged early: latency hides under af load + init
  stage64(embbf,               (unsigned char*)smem,         t);
  stage64(embbf + 64 * EMB_C,  (unsigned char*)smem + 32768, t);

  if (t < 256) { keys_l[t] = 0u; xn_l[t] = xn_g[n0 + t]; }
  for (int i = t; i < 1024; i += 512) cjl[i] = 0.375f - 0.5f * enorm[i];

  // ---- af: direct coalesced loads from fragment-ordered A ----
  bf16x8 af[4][8];
  const uint4* Ab = (const uint4*)A + (size_t)blockIdx.x * 8192;
#pragma unroll
  for (int i = 0; i < 4; ++i)
#pragma unroll
    for (int s = 0; s < 8; ++s) {
      uint4 q = Ab[((g * 4 + i) * 8 + s) * 64 + lane];   // 1KB/wave coalesced
      af[i][s] = __builtin_bit_cast(bf16x8, q);
    }
  __syncthreads();   // LDS init visible; B(0)/B(1) glds drained

  // ---- K-loop: 16 tiles of 64 k; 4-buf rotation, 1 barrier + counted vmcnt ----
  unsigned best[4][4] = {};
  for (int kt = 0; kt < 16; ++kt) {
    if (kt < 14)
      stage64(embbf + (size_t)(kt + 2) * 64 * EMB_C,
              (unsigned char*)smem + (((kt + 2) & 3) << 15), t);
    // outstanding stages: kt,kt+1,kt+2 = 12 chunks -> wait oldest stage (4 each)
    if (kt < 14)       asm volatile("s_waitcnt vmcnt(8)" ::: "memory");
    else if (kt == 14) asm volatile("s_waitcnt vmcnt(4)" ::: "memory");
    else               asm volatile("s_waitcnt vmcnt(0)" ::: "memory");
    __builtin_amdgcn_s_barrier();              // all waves' stage(kt) landed
    __builtin_amdgcn_sched_barrier(0);         // no LDS-read hoist above
    const unsigned char* srcB = (const unsigned char*)smem + ((kt & 3) << 15);
    float cj[2]; unsigned kp[2];
#pragma unroll
    for (int j = 0; j < 2; ++j) {
      int k = kt * 64 + h2 * 32 + j * 16 + lr;
      cj[j] = cjl[k];
      kp[j] = 1023u - (unsigned)k;
    }
    f32x4 acc[4][2] = {};
#pragma unroll
    for (int s = 0; s < 8; ++s) {
      int cc = s * 4 + quad;
      int pos = ((cc >> 3) << 3) | ((cc & 7) ^ (lr & 7));   // B swizzle (rB&7==lr&7)
      bf16x8 bf[2];
#pragma unroll
      for (int j = 0; j < 2; ++j)
        bf[j] = *(const bf16x8*)(srcB + (h2 * 32 + j * 16 + lr) * 512 + pos * 16);
#pragma unroll
      for (int i = 0; i < 4; ++i)
#pragma unroll
        for (int j = 0; j < 2; ++j)
          acc[i][j] = __builtin_amdgcn_mfma_f32_16x16x32_bf16(af[i][s], bf[j], acc[i][j], 0, 0, 0);
    }
    // fold argmin keys: f = dot + 0.375 - 0.5||e||^2 in (0.04,0.71) -> positive
    // float u32-order-correct; low 10 mantissa bits carry (1023-k).
#pragma unroll
    for (int i = 0; i < 4; ++i)
#pragma unroll
      for (int j = 0; j < 2; ++j)
#pragma unroll
        for (int r = 0; r < 4; ++r) {
          float f = acc[i][j][r] + cj[j];
          unsigned key = (__float_as_uint(f) & 0xFFFFFC00u) | kp[j];
          best[i][r] = best[i][r] > key ? best[i][r] : key;
        }
  }
  __syncthreads();   // k-loop complete before keys_l atomics phase

  // ---- combine keys across k-lanes; k-halves via LDS atomicMax ----
#pragma unroll
  for (int i = 0; i < 4; ++i)
#pragma unroll
    for (int r = 0; r < 4; ++r) {
      unsigned v = best[i][r];
#pragma unroll
      for (int m = 1; m < 16; m <<= 1) {
        unsigned o = (unsigned)__shfl_xor((int)v, m, 64);
        v = v > o ? v : o;
      }
      if (lr == 0) atomicMax(&keys_l[g * 64 + i * 16 + quad * 4 + r], v);
    }
  __syncthreads();

  // ---- keys export + loss partial: d2 = ||x||^2 + 0.75 - 2*f_hat ----
  if (t < 256) {
    unsigned key = keys_l[t];
    keys_g[n0 + t] = key;
    float fh = __uint_as_float(key & 0xFFFFFC00u);
    float lsum = xn_l[t] + 0.75f - 2.0f * fh;
    for (int m = 32; m; m >>= 1) lsum += __shfl_down(lsum, m, 64);
    if (lane == 0) red[w] = lsum;
  }
  __syncthreads();
  if (t == 0)
    atomicAdd(loss, red[0] + red[1] + red[2] + red[3]);   // device-scope
}

// ================= output kernel: gather + transpose + store =================
// 2048 blocks x 256 thr, 16.6KB LDS -> 8 blocks/CU = 32 waves/CU (proven R12:
// ~5.3 TB/s). Stride-65 LDS tile conflict-free both directions; 256B/wave
// scalar-row stores alignment-proof vs out+1. Loss finalize here (stream
// order guarantees all k_main atomics complete).
__global__ __launch_bounds__(256) void
k_out(const float* __restrict__ emb, const unsigned* __restrict__ keys_g,
      const float* __restrict__ loss, float* __restrict__ out) {
  __shared__ float tile[64 * 65];            // 16.25 KB
  __shared__ int   idx_l[64];
  int e  = blockIdx.x;
  int nt = e >> 1, cH = e & 1;
  int n0 = nt * 64;
  int b  = n0 >> 12, hw0 = n0 & 4095;
  int t = threadIdx.x, w = t >> 6, lane = t & 63;
  if (e == 0 && t == 0)
    out[0] = 1.0625f * (*loss) / 16777216.0f;
  if (t < 64) idx_l[t] = 1023 - (int)(keys_g[n0 + t] & 1023u);
  __syncthreads();
  int nn = t >> 2, ch = t & 3;               // 4 threads per n
  const float* er = emb + (size_t)idx_l[nn] * EMB_C + cH * 128;
  float* ob = out + 1 + (size_t)b * (EMB_C * HWB) + (size_t)cH * 128 * HWB + hw0;
  for (int p = 0; p < 2; ++p) {              // 2 passes of 64 c
    if (p) __syncthreads();                  // pass-0 stores done before rewrite
#pragma unroll
    for (int q = 0; q < 4; ++q) {            // 4 lanes x 16B = 64B/line per (nn,q)
      f32x4 v = *(const f32x4*)(er + p * 64 + q * 16 + ch * 4);
#pragma unroll
      for (int m = 0; m < 4; ++m)
        tile[(q * 16 + ch * 4 + m) * 65 + nn] = v[m];
    }
    __syncthreads();
#pragma unroll
    for (int cc = 0; cc < 16; ++cc) {        // wave w: c-rows w*16..w*16+15
      int cl = w * 16 + cc;
      ob[(size_t)(p * 64 + cl) * HWB + lane] = tile[cl * 65 + lane];  // 256B/wave
    }
  }
}

extern "C" void kernel_launch(void* const* d_in, const int* in_sizes, int n_in,
                              void* d_out, int out_size, void* d_ws, size_t ws_size,
                              hipStream_t stream) {
  const float* x   = (const float*)d_in[0];   // [16,256,64,64]
  const float* emb = (const float*)d_in[1];   // [1024,256]
  float* out = (float*)d_out;                 // [1 + 16777216]
  char*  ws  = (char*)d_ws;

  unsigned short* emb_bf = (unsigned short*)ws;                 // 512 KB
  float*          enorm  = (float*)(ws + 524288);               // 4 KB
  float*          loss   = (float*)(ws + 528384);               // 4 B
  float*          xn_g   = (float*)(ws + 532480);               // 256 KB
  unsigned*       keys_g = (unsigned*)(ws + 794624);            // 256 KB

  // A (bf16, fragment-ordered, 32 MB) lives inside the out payload at a 16B
  // offset. k_main reads it before k_out overwrites out[1..] (stream order —
  // proven safe R2-R6).
  unsigned short* A = (unsigned short*)(out + 4);

  hipFuncSetAttribute((const void*)k_main,
                      hipFuncAttributeMaxDynamicSharedMemorySize, LDS_BYTES);

  k_emb <<<dim3(EMB_K),      dim3(EMB_C), 0,         stream>>>(emb, emb_bf, enorm, loss);
  k_tr  <<<dim3(NPIX / 64),  dim3(512),   0,         stream>>>(x, A, xn_g);
  k_main<<<dim3(NPIX / 256), dim3(512),   LDS_BYTES, stream>>>(A, emb_bf, enorm, xn_g,
                                                               keys_g, loss);
  k_out <<<dim3(NPIX / 32),  dim3(256),   0,         stream>>>(emb, keys_g, loss, out);
}